// Round 1
// baseline (356.617 us; speedup 1.0000x reference)
//
#include <hip/hip_runtime.h>
#include <hip/hip_bf16.h>
#include <math.h>

// ImageTokenization: conv3x3(64->64)+BN+GELU -> patches(masked) -> proj GEMM(2304->768)+GELU
// Inputs fp32, outputs fp32; compute in bf16 MFMA (tolerance 8*2^-8).
// d_out (fp32) = [tokens 8192x768][patches 8192x2304].

typedef unsigned short u16;
typedef __bf16 bf16x8 __attribute__((ext_vector_type(8)));
typedef float f32x4 __attribute__((ext_vector_type(4)));

#define NFRM 32
#define CH 64
#define HW 96
#define HWP 98
#define KP 2304
#define DIMN 768
#define MTOK 8192
#define TOKN (MTOK * DIMN)          // 6,291,456 floats
#define NPAT (MTOK * KP)            // 18,874,368 floats
// ws layout (u16 units): [xhwc 19,668,992 | bp 36,864 | pw 1,769,472]; xhwc reused as A-bf16
#define XHWC_ELEMS ((size_t)NFRM * HWP * HWP * CH)
#define BP_OFF XHWC_ELEMS
#define PW_OFF (BP_OFF + 36864)
#define BSTR 328                    // padded B-row stride (656B = 164 dw ≡ 4 mod 32 → 2-way free)

static __device__ __forceinline__ u16 f2b(float f) {
  unsigned u = __builtin_bit_cast(unsigned, f);
  u += 0x7fffu + ((u >> 16) & 1u);
  return (u16)(u >> 16);
}
static __device__ __forceinline__ float gelu_f(float x) {
  return 0.5f * x * (1.0f + erff(x * 0.7071067811865476f));
}

typedef __attribute__((address_space(3))) unsigned int lds_uint;
typedef __attribute__((address_space(1))) const unsigned int g_uint;
static __device__ __forceinline__ void gload16(const u16* g, u16* s) {
  // wave-uniform LDS base; HW writes base + lane*16; global src is per-lane.
  __builtin_amdgcn_global_load_lds((g_uint*)g, (lds_uint*)s, 16, 0, 0);
}

// -------- kernel 1: x[32][64][96][96] fp32 -> xhwc[32][98][98][64] bf16 (halo pre-zeroed) ----
__global__ __launch_bounds__(256) void k_transpose(const float* __restrict__ x,
                                                   u16* __restrict__ xhwc) {
  __shared__ u16 tile[96 * 66];  // [w][ci], stride 66 breaks bank collisions
  const int f = blockIdx.x / 96, h = blockIdx.x % 96;
  const int t = threadIdx.x;
  const float* xp = x + (size_t)f * CH * HW * HW + (size_t)h * HW;
#pragma unroll
  for (int k = 0; k < 6; ++k) {
    int e = (k * 256 + t) * 4;
    int ci = e / 96, w = e % 96;
    float4 v = *(const float4*)(xp + (size_t)ci * (HW * HW) + w);
    tile[(w + 0) * 66 + ci] = f2b(v.x);
    tile[(w + 1) * 66 + ci] = f2b(v.y);
    tile[(w + 2) * 66 + ci] = f2b(v.z);
    tile[(w + 3) * 66 + ci] = f2b(v.w);
  }
  __syncthreads();
  u16* op = xhwc + ((size_t)(f * HWP + h + 1) * HWP + 1) * CH;
#pragma unroll
  for (int k = 0; k < 12; ++k) {
    int e2 = (k * 256 + t) * 2;
    int w = e2 >> 6, ci = e2 & 63;
    *(unsigned*)(op + e2) = *(const unsigned*)(&tile[w * 66 + ci]);
  }
}

// -------- kernel 2: conv_w[co][ci][3][3] fp32 -> bp[co][tap*64+ci] bf16 --------
__global__ __launch_bounds__(256) void k_bpack(const float* __restrict__ w,
                                               u16* __restrict__ bp) {
  int e = blockIdx.x * 256 + threadIdx.x;  // < 36864
  int co = e / 576, r = e - co * 576, tap = r >> 6, ci = r & 63;
  bp[e] = f2b(w[(co * 64 + ci) * 9 + tap]);
}

// -------- kernel 3: proj_w fp32 -> bf16 --------
__global__ __launch_bounds__(256) void k_pw(const float* __restrict__ pw,
                                            u16* __restrict__ dst) {
  int e = (blockIdx.x * 256 + threadIdx.x) * 4;  // < 1,769,472
  float4 v = *(const float4*)(pw + e);
  ushort4 o;
  o.x = f2b(v.x); o.y = f2b(v.y); o.z = f2b(v.z); o.w = f2b(v.w);
  *(ushort4*)(dst + e) = o;
}

// -------- kernel 4: strip conv. Block = frame x patch-row (16 patches, 6x96 px). --------
// Input strip (8 rows x 98 cols x 64 ch bf16 = 100,352B contiguous) staged ONCE via
// global_load_lds w=16, XOR-granule-swizzled (g ^= pix&7) for conflict-free ds_read_b128.
// B staged in 2 phases (taps 0..4 / 5..8). 3 barriers/block vs 18 in tap-restaged version.
// 512 threads = 8 waves (4 M-waves x 2 N-waves); per wave M=144 (9 frags) x N=32 (2 frags).
// Tap order 0..8, ks 0..1 -> accumulation order identical to previous kernel (bit-exact).
template <int T0, int NT>
static __device__ __forceinline__ void conv_tapblock(
    const u16* __restrict__ bw, u16* Bs2, const char* asb,
    f32x4 (&acc)[9][2], const int (&pb)[9],
    const int t, const int wn, const int lm, const int quad) {
  // stage B taps T0..T0+NT-1 : Bs2[co][ (tap-T0)*64 + ci ], padded stride BSTR
  for (int e = t; e < 64 * NT * 8; e += 512) {
    const int co = e / (NT * 8), kk = e - co * (NT * 8);
    *(uint4*)&Bs2[co * BSTR + kk * 8] = *(const uint4*)&bw[co * 576 + T0 * 64 + kk * 8];
  }
  __syncthreads();  // drains gload_lds vmcnt (phase 1) + B ds_writes
#pragma unroll
  for (int tp = 0; tp < NT; ++tp) {
    const int tap = T0 + tp;
    const int di = tap / 3, dj = tap - (tap / 3) * 3;
#pragma unroll
    for (int ks = 0; ks < 2; ++ks) {
      const int kq = ks * 4 + quad;
      const bf16x8 b0 = *(const bf16x8*)&Bs2[(wn * 32 + lm) * BSTR + tp * 64 + ks * 32 + quad * 8];
      const bf16x8 b1 = *(const bf16x8*)&Bs2[(wn * 32 + 16 + lm) * BSTR + tp * 64 + ks * 32 + quad * 8];
#pragma unroll
      for (int mf = 0; mf < 9; ++mf) {
        const int p = pb[mf] + di * 98 + dj;  // pixel in 8x98 strip
        const bf16x8 a = *(const bf16x8*)(asb + p * 128 + ((kq ^ (p & 7)) << 4));
        acc[mf][0] = __builtin_amdgcn_mfma_f32_16x16x32_bf16(a, b0, acc[mf][0], 0, 0, 0);
        acc[mf][1] = __builtin_amdgcn_mfma_f32_16x16x32_bf16(a, b1, acc[mf][1], 0, 0, 0);
      }
    }
  }
}

__global__ __launch_bounds__(512, 2) void k_conv(
    const u16* __restrict__ xhwc, const u16* __restrict__ bw,
    const float* __restrict__ cb, const float* __restrict__ gma,
    const float* __restrict__ bta, const float* __restrict__ mu,
    const float* __restrict__ var, const float* __restrict__ msk,
    float* __restrict__ pout) {
  __shared__ alignas(16) u16 As2[8 * 98 * 64];   // 100,352 B, granule-swizzled
  __shared__ alignas(16) u16 Bs2[64 * BSTR];     // 41,984 B  (total 142,336 B LDS)
  const int f = blockIdx.x >> 4, pr0 = blockIdx.x & 15;
  const int t = threadIdx.x;
  const int wid = t >> 6, l = t & 63, quad = l >> 4, lm = l & 15;
  const int wm = wid >> 1, wn = wid & 1;

  // ---- stage A strip: xhwc rows 6*pr0 .. 6*pr0+7, full 98-col width (contiguous) ----
  // dest linear; source pre-swizzled so a swizzled READ sees granule kq at g = kq^(p&7).
  const u16* sbase = xhwc + ((size_t)f * HWP + pr0 * 6) * (HWP * CH);
  for (int c = wid; c < 98; c += 8) {            // 98 x 1KB chunks, wave-uniform dest
    const int p = c * 8 + (l >> 3);              // pixel 0..783
    const int g = (l & 7) ^ (p & 7);             // inverse-swizzled source granule
    gload16(sbase + p * 64 + g * 8, &As2[c * 512]);
  }

  int pb[9];
#pragma unroll
  for (int mf = 0; mf < 9; ++mf) {               // per-frag pixel base (+lane col)
    const int i16 = wm * 9 + mf;                 // 16-px run; 16|96 so runs never wrap
    pb[mf] = (i16 / 6) * 98 + (i16 % 6) * 16 + lm;
  }
  f32x4 acc[9][2];
#pragma unroll
  for (int mf = 0; mf < 9; ++mf) {
    acc[mf][0] = (f32x4){0.f, 0.f, 0.f, 0.f};
    acc[mf][1] = (f32x4){0.f, 0.f, 0.f, 0.f};
  }
  const char* asb = (const char*)As2;

  conv_tapblock<0, 5>(bw, Bs2, asb, acc, pb, t, wn, lm, quad);
  __syncthreads();                               // all Bs2 reads done before restage
  conv_tapblock<5, 4>(bw, Bs2, asb, acc, pb, t, wn, lm, quad);

  // ---- epilogue: BN + GELU + mask -> patches fp32 ----
#pragma unroll
  for (int nf = 0; nf < 2; ++nf) {
    const int co = wn * 32 + nf * 16 + lm;       // C/D col = lane&15
    const float scv = gma[co] * rsqrtf(var[co] + 1e-5f);
    const float b2v = (cb[co] - mu[co]) * scv + bta[co];
#pragma unroll
    for (int mf = 0; mf < 9; ++mf) {
#pragma unroll
      for (int rg = 0; rg < 4; ++rg) {
        const int ml = wm * 144 + mf * 16 + quad * 4 + rg;  // C/D row = quad*4+reg
        const int rr = ml / 96, w = ml - rr * 96;
        const int n = pr0 * 16 + w / 6;
        const int jj = rr * 6 + (w - (w / 6) * 6);
        float v = acc[mf][nf][rg] * scv + b2v;
        v = gelu_f(v) * msk[jj];
        pout[((size_t)(f * 256 + n) * 64 + co) * 36 + jj] = v;
      }
    }
  }
}

// -------- kernel 5: patches fp32 -> A bf16 (into dead xhwc region) --------
__global__ __launch_bounds__(256) void k_cvt(const float* __restrict__ pat,
                                             u16* __restrict__ abf) {
  int e = (blockIdx.x * 256 + threadIdx.x) * 4;  // < 18,874,368
  float4 v = *(const float4*)(pat + e);
  ushort4 o;
  o.x = f2b(v.x); o.y = f2b(v.y); o.z = f2b(v.z); o.w = f2b(v.w);
  *(ushort4*)(abf + e) = o;
}

// -------- kernel 6: tokens = gelu(A @ proj_w^T + proj_b), fp32 out --------
// M=8192 K=2304 N=768; BM=128 BN=64 BK=32; m97 structure: global_load_lds w=16 into
// linear LDS (the +69% m93->m97 lever); bn-fastest block order for A L2 reuse.
__global__ __launch_bounds__(256) void k_gemm(const u16* __restrict__ A,
                                              const u16* __restrict__ Bt,
                                              const float* __restrict__ pb,
                                              float* __restrict__ out) {
  __shared__ alignas(16) u16 As[128 * 32];  // 8KB linear
  __shared__ alignas(16) u16 Bs[64 * 32];   // 4KB linear
  const int bn = blockIdx.x % 12, bm = blockIdx.x / 12;
  const int m0 = bm * 128, n0 = bn * 64;
  const int t = threadIdx.x, wv = t >> 6, l = t & 63, quad = l >> 4, lm = l & 15;

  // per-lane sources for gload_lds chunks (chunk = 16 rows x 64B; lane i: row i>>2, gran i&3)
  const int crow = l >> 2, cg = (l & 3) * 8;
  const u16* aS0 = A + (size_t)(m0 + wv * 32 + crow) * KP + cg;
  const u16* aS1 = A + (size_t)(m0 + wv * 32 + 16 + crow) * KP + cg;
  const u16* bS = Bt + (size_t)(n0 + wv * 16 + crow) * KP + cg;
  u16* aD0 = &As[wv * 1024];       // wave-uniform dests
  u16* aD1 = &As[wv * 1024 + 512];
  u16* bD = &Bs[wv * 512];

  f32x4 acc[2][4];
#pragma unroll
  for (int s = 0; s < 2; ++s)
#pragma unroll
    for (int u = 0; u < 4; ++u) acc[s][u] = (f32x4){0.f, 0.f, 0.f, 0.f};

  for (int k0 = 0; k0 < KP; k0 += 32) {
    __syncthreads();
    gload16(aS0 + k0, aD0);
    gload16(aS1 + k0, aD1);
    gload16(bS + k0, bD);
    __syncthreads();               // vmcnt(0) drain
    const int ko = quad * 8;
    const bf16x8 a0 = *(const bf16x8*)&As[(wv * 32 + lm) * 32 + ko];
    const bf16x8 a1 = *(const bf16x8*)&As[(wv * 32 + 16 + lm) * 32 + ko];
#pragma unroll
    for (int u = 0; u < 4; ++u) {
      const bf16x8 b = *(const bf16x8*)&Bs[(u * 16 + lm) * 32 + ko];
      acc[0][u] = __builtin_amdgcn_mfma_f32_16x16x32_bf16(a0, b, acc[0][u], 0, 0, 0);
      acc[1][u] = __builtin_amdgcn_mfma_f32_16x16x32_bf16(a1, b, acc[1][u], 0, 0, 0);
    }
  }
#pragma unroll
  for (int u = 0; u < 4; ++u) {
    const int n = n0 + u * 16 + lm;
    const float bias = pb[n];
#pragma unroll
    for (int s = 0; s < 2; ++s) {
#pragma unroll
      for (int rg = 0; rg < 4; ++rg) {
        const int m = m0 + wv * 32 + s * 16 + quad * 4 + rg;
        out[(size_t)m * DIMN + n] = gelu_f(acc[s][u][rg] + bias);
      }
    }
  }
}

extern "C" void kernel_launch(void* const* d_in, const int* in_sizes, int n_in,
                              void* d_out, int out_size, void* d_ws, size_t ws_size,
                              hipStream_t stream) {
  const float* x = (const float*)d_in[0];
  const float* conv_w = (const float*)d_in[1];
  const float* conv_b = (const float*)d_in[2];
  const float* bn_gamma = (const float*)d_in[3];
  const float* bn_beta = (const float*)d_in[4];
  const float* bn_mean = (const float*)d_in[5];
  const float* bn_var = (const float*)d_in[6];
  const float* proj_w = (const float*)d_in[7];
  const float* proj_b = (const float*)d_in[8];
  const float* mask = (const float*)d_in[9];
  float* out = (float*)d_out;         // [tokens][patches], fp32
  float* patches = out + TOKN;
  u16* ws = (u16*)d_ws;
  u16* xhwc = ws;                     // later reused as A bf16
  u16* bp = ws + BP_OFF;
  u16* pw = ws + PW_OFF;

  hipMemsetAsync(d_ws, 0, XHWC_ELEMS * sizeof(u16), stream);  // zero halo
  k_transpose<<<NFRM * HW, 256, 0, stream>>>(x, xhwc);
  k_bpack<<<144, 256, 0, stream>>>(conv_w, bp);
  k_pw<<<1728, 256, 0, stream>>>(proj_w, pw);
  k_conv<<<NFRM * 16, 512, 0, stream>>>(xhwc, bp, conv_b, bn_gamma, bn_beta,
                                        bn_mean, bn_var, mask, patches);
  k_cvt<<<18432, 256, 0, stream>>>(patches, xhwc);  // xhwc dead after k_conv
  k_gemm<<<64 * 12, 256, 0, stream>>>(xhwc, pw, proj_b, out);
}

// Round 2
// 320.394 us; speedup vs baseline: 1.1131x; 1.1131x over previous
//
#include <hip/hip_runtime.h>
#include <hip/hip_bf16.h>
#include <math.h>

// ImageTokenization: conv3x3(64->64)+BN+GELU -> patches(masked) -> proj GEMM(2304->768)+GELU
// Inputs fp32, outputs fp32; compute in bf16 MFMA (tolerance 8*2^-8).
// d_out (fp32) = [tokens 8192x768][patches 8192x2304].

typedef unsigned short u16;
typedef __bf16 bf16x8 __attribute__((ext_vector_type(8)));
typedef float f32x4 __attribute__((ext_vector_type(4)));

#define NFRM 32
#define CH 64
#define HW 96
#define HWP 98
#define KP 2304
#define DIMN 768
#define MTOK 8192
#define TOKN (MTOK * DIMN)          // 6,291,456 floats
#define NPAT (MTOK * KP)            // 18,874,368 floats
// ws layout (u16 units): [xhwc 19,668,992 | bp 36,864 | pw 1,769,472]; xhwc reused as A-bf16
#define XHWC_ELEMS ((size_t)NFRM * HWP * HWP * CH)
#define BP_OFF XHWC_ELEMS
#define PW_OFF (BP_OFF + 36864)
#define BSTR 200                    // B LDS row stride (u16): 192 data + 8 pad (100dw ≡ 4 mod 32)

static __device__ __forceinline__ u16 f2b(float f) {
  unsigned u = __builtin_bit_cast(unsigned, f);
  u += 0x7fffu + ((u >> 16) & 1u);
  return (u16)(u >> 16);
}
static __device__ __forceinline__ float gelu_f(float x) {
  return 0.5f * x * (1.0f + erff(x * 0.7071067811865476f));
}

typedef __attribute__((address_space(3))) unsigned int lds_uint;
typedef __attribute__((address_space(1))) const unsigned int g_uint;
static __device__ __forceinline__ void gload16(const u16* g, u16* s) {
  // wave-uniform LDS base; HW writes base + lane*16; global src is per-lane.
  __builtin_amdgcn_global_load_lds((g_uint*)g, (lds_uint*)s, 16, 0, 0);
}

// -------- kernel 1: x[32][64][96][96] fp32 -> xhwc[32][98][98][64] bf16 (halo pre-zeroed) ----
__global__ __launch_bounds__(256) void k_transpose(const float* __restrict__ x,
                                                   u16* __restrict__ xhwc) {
  __shared__ u16 tile[96 * 66];  // [w][ci], stride 66 breaks bank collisions
  const int f = blockIdx.x / 96, h = blockIdx.x % 96;
  const int t = threadIdx.x;
  const float* xp = x + (size_t)f * CH * HW * HW + (size_t)h * HW;
#pragma unroll
  for (int k = 0; k < 6; ++k) {
    int e = (k * 256 + t) * 4;
    int ci = e / 96, w = e % 96;
    float4 v = *(const float4*)(xp + (size_t)ci * (HW * HW) + w);
    tile[(w + 0) * 66 + ci] = f2b(v.x);
    tile[(w + 1) * 66 + ci] = f2b(v.y);
    tile[(w + 2) * 66 + ci] = f2b(v.z);
    tile[(w + 3) * 66 + ci] = f2b(v.w);
  }
  __syncthreads();
  u16* op = xhwc + ((size_t)(f * HWP + h + 1) * HWP + 1) * CH;
#pragma unroll
  for (int k = 0; k < 12; ++k) {
    int e2 = (k * 256 + t) * 2;
    int w = e2 >> 6, ci = e2 & 63;
    *(unsigned*)(op + e2) = *(const unsigned*)(&tile[w * 66 + ci]);
  }
}

// -------- kernel 2: conv_w[co][ci][3][3] fp32 -> bp[co][tap*64+ci] bf16 --------
__global__ __launch_bounds__(256) void k_bpack(const float* __restrict__ w,
                                               u16* __restrict__ bp) {
  int e = blockIdx.x * 256 + threadIdx.x;  // < 36864
  int co = e / 576, r = e - co * 576, tap = r >> 6, ci = r & 63;
  bp[e] = f2b(w[(co * 64 + ci) * 9 + tap]);
}

// -------- kernel 3: proj_w fp32 -> bf16 --------
__global__ __launch_bounds__(256) void k_pw(const float* __restrict__ pw,
                                            u16* __restrict__ dst) {
  int e = (blockIdx.x * 256 + threadIdx.x) * 4;  // < 1,769,472
  float4 v = *(const float4*)(pw + e);
  ushort4 o;
  o.x = f2b(v.x); o.y = f2b(v.y); o.z = f2b(v.z); o.w = f2b(v.w);
  *(ushort4*)(dst + e) = o;
}

// -------- kernel 4: half-strip conv. Block = frame x 8 patches (6 rows x 48 cols). ----------
// A: 8 rows x 50 cols x 64ch bf16 = 51,200B staged ONCE (gload_lds w=16, granule-swizzled).
// B: 3-tap phases (taps 3ph..3ph+2 = 24KB from hot L2) -> tap order 0..8 preserved exactly.
// LDS total 76,800B -> 2 blocks/CU (round-1's 142KB forced 1/CU = no overlap).
// Epilogue: results -> LDS in pout layout -> lane-consecutive float4 stores (round-1's
// scattered scalar stores caused 2.65x HBM write amplification, 200MB vs 75.5MB).
// Accumulation chain (tap 0..8 outer, ci-half inner, nf order) BIT-IDENTICAL to rounds 0/1.
__global__ __launch_bounds__(256, 2) void k_conv(
    const u16* __restrict__ xhwc, const u16* __restrict__ bw,
    const float* __restrict__ cb, const float* __restrict__ gma,
    const float* __restrict__ bta, const float* __restrict__ mu,
    const float* __restrict__ var, const float* __restrict__ msk,
    float* __restrict__ pout) {
  __shared__ alignas(16) char SMEM[76800];
  u16* Asm = (u16*)SMEM;                 // [400 px][64 u16], granule-swizzled
  u16* Bsm = (u16*)(SMEM + 51200);       // [64 co][BSTR u16], 3 taps per phase
  float* Fsm = (float*)SMEM;             // epilogue: 18,432 floats (73,728B)

  const int bx = blockIdx.x;
  const int f = bx >> 5, rem = bx & 31, pr = rem >> 1, half = rem & 1;
  const int t = threadIdx.x, wv = t >> 6, l = t & 63, quad = l >> 4, lm = l & 15;
  const int wm = wv >> 1, wn = wv & 1;

  // ---- stage A once: xhwc rows pr*6 .. pr*6+7, cols half*48 .. +49 (halo included) ----
  // 50 chunks x 1KB; dest linear; source granule pre-swizzled: slot s of pixel p holds
  // logical granule s^(p&7), so reads at slot kq^(p&7) are conflict-free.
  const u16* sbase = xhwc + (((size_t)f * HWP + pr * 6) * HWP + half * 48) * CH;
  const int pc = l >> 3;                 // pixel-in-chunk 0..7  (== p&7)
  const int gsw = (l & 7) ^ pc;          // source granule for dest slot (l&7)
  for (int c = wv; c < 50; c += 4) {
    const int p = c * 8 + pc;            // strip pixel 0..399
    const int row = p / 50, ac = p - row * 50;
    gload16(sbase + ((size_t)row * HWP + ac) * CH + gsw * 8, Asm + c * 512);
  }

  int pb[9];
#pragma unroll
  for (int mf = 0; mf < 9; ++mf) {       // per-frag pixel base (strip = [6 out-rows][48 cols])
    const int i16 = wm * 9 + mf;         // 16-px run index; 3 runs per row
    pb[mf] = (i16 / 3) * 50 + (i16 % 3) * 16 + lm;
  }
  f32x4 acc[9][2];
#pragma unroll
  for (int mf = 0; mf < 9; ++mf) {
    acc[mf][0] = (f32x4){0.f, 0.f, 0.f, 0.f};
    acc[mf][1] = (f32x4){0.f, 0.f, 0.f, 0.f};
  }

  // ---- 3 phases: taps {0,1,2},{3,4,5},{6,7,8}; di = ph, dj = tp ----
#pragma unroll
  for (int ph = 0; ph < 3; ++ph) {
    if (ph > 0) __syncthreads();         // all Bsm reads of previous phase done
    // stage B taps 3ph..3ph+2: 64co x 24 granules (192 u16), padded stride BSTR
    for (int e = t; e < 1536; e += 256) {
      const int co = e / 24, kk = e - co * 24;
      *(uint4*)&Bsm[co * BSTR + kk * 8] =
          *(const uint4*)&bw[co * 576 + ph * 192 + kk * 8];
    }
    __syncthreads();                     // B ready (ph 0: also drains A gload_lds vmcnt)
#pragma unroll
    for (int tp = 0; tp < 3; ++tp) {
      const int di = ph, dj = tp;        // tap = 3*ph + tp
#pragma unroll
      for (int ks = 0; ks < 2; ++ks) {
        const int kq = ks * 4 + quad;
        const bf16x8 b0 = *(const bf16x8*)&Bsm[(wn * 32 + lm) * BSTR + tp * 64 + ks * 32 + quad * 8];
        const bf16x8 b1 = *(const bf16x8*)&Bsm[(wn * 32 + 16 + lm) * BSTR + tp * 64 + ks * 32 + quad * 8];
#pragma unroll
        for (int mf = 0; mf < 9; ++mf) {
          const int p = pb[mf] + di * 50 + dj;
          const bf16x8 a = *(const bf16x8*)&Asm[p * 64 + ((kq ^ (p & 7)) << 3)];
          acc[mf][0] = __builtin_amdgcn_mfma_f32_16x16x32_bf16(a, b0, acc[mf][0], 0, 0, 0);
          acc[mf][1] = __builtin_amdgcn_mfma_f32_16x16x32_bf16(a, b1, acc[mf][1], 0, 0, 0);
        }
      }
    }
  }

  // ---- epilogue: BN + GELU + mask -> LDS (pout layout) -> coalesced float4 stores ----
  __syncthreads();                       // all Asm/Bsm reads done; reuse LDS as float buffer
#pragma unroll
  for (int nf = 0; nf < 2; ++nf) {
    const int co = wn * 32 + nf * 16 + lm;   // C/D col = lane&15
    const float scv = gma[co] * rsqrtf(var[co] + 1e-5f);
    const float b2v = (cb[co] - mu[co]) * scv + bta[co];
#pragma unroll
    for (int mf = 0; mf < 9; ++mf) {
#pragma unroll
      for (int rg = 0; rg < 4; ++rg) {
        const int sp = wm * 144 + mf * 16 + quad * 4 + rg;  // strip pixel (row = quad*4+rg)
        const int orow = sp / 48, oc = sp - orow * 48;
        const int nl = oc / 6, pj = oc - nl * 6;
        const int jj = orow * 6 + pj;
        float v = acc[mf][nf][rg] * scv + b2v;
        v = gelu_f(v) * msk[jj];
        Fsm[nl * 2304 + co * 36 + jj] = v;
      }
    }
  }
  __syncthreads();
  float* pbase = pout + (size_t)(f * 256 + pr * 16 + half * 8) * KP;
#pragma unroll
  for (int k = 0; k < 18; ++k) {
    const int li = t + k * 256;          // 4,608 float4 per block, dense
    *(float4*)&pbase[li * 4] = *(const float4*)&Fsm[li * 4];
  }
}

// -------- kernel 5: patches fp32 -> A bf16 (into dead xhwc region) --------
__global__ __launch_bounds__(256) void k_cvt(const float* __restrict__ pat,
                                             u16* __restrict__ abf) {
  int e = (blockIdx.x * 256 + threadIdx.x) * 4;  // < 18,874,368
  float4 v = *(const float4*)(pat + e);
  ushort4 o;
  o.x = f2b(v.x); o.y = f2b(v.y); o.z = f2b(v.z); o.w = f2b(v.w);
  *(ushort4*)(abf + e) = o;
}

// -------- kernel 6: tokens = gelu(A @ proj_w^T + proj_b), fp32 out --------
// M=8192 K=2304 N=768; BM=128 BN=64 BK=64 (barriers halved vs BK=32); gload_lds w=16 with
// both-sides granule swizzle (slot s of row r holds logical s^(r&7)) -> conflict-free
// ds_read_b128. ks order inside a step preserves the exact BK=32 accumulation chain.
__global__ __launch_bounds__(256) void k_gemm(const u16* __restrict__ A,
                                              const u16* __restrict__ Bt,
                                              const float* __restrict__ pb,
                                              float* __restrict__ out) {
  __shared__ alignas(16) u16 As[128 * 64];  // 16KB
  __shared__ alignas(16) u16 Bs[64 * 64];   // 8KB
  const int bn = blockIdx.x % 12, bm = blockIdx.x / 12;
  const int m0 = bm * 128, n0 = bn * 64;
  const int t = threadIdx.x, wv = t >> 6, l = t & 63, quad = l >> 4, lm = l & 15;
  const int pc = l >> 3;                 // chunk-local row (== row&7)
  const int gsw = (l & 7) ^ pc;          // pre-swizzled source granule

  f32x4 acc[2][4];
#pragma unroll
  for (int s = 0; s < 2; ++s)
#pragma unroll
    for (int u = 0; u < 4; ++u) acc[s][u] = (f32x4){0.f, 0.f, 0.f, 0.f};

  for (int k0 = 0; k0 < KP; k0 += 64) {
    __syncthreads();
    // 24 chunks of 1KB (As 16 + Bs 8); chunk = 8 rows x 128B; wave-uniform dests
    for (int c = wv; c < 24; c += 4) {
      if (c < 16) {
        const int row = c * 8 + pc;
        gload16(A + (size_t)(m0 + row) * KP + k0 + gsw * 8, As + c * 512);
      } else {
        const int row = (c - 16) * 8 + pc;
        gload16(Bt + (size_t)(n0 + row) * KP + k0 + gsw * 8, Bs + (c - 16) * 512);
      }
    }
    __syncthreads();                     // vmcnt(0) drain
#pragma unroll
    for (int ks = 0; ks < 2; ++ks) {
      const int gx = ((ks * 4 + quad) ^ (lm & 7)) << 3;  // row&7 == lm&7 for all reads
      const bf16x8 a0 = *(const bf16x8*)&As[(wv * 32 + lm) * 64 + gx];
      const bf16x8 a1 = *(const bf16x8*)&As[(wv * 32 + 16 + lm) * 64 + gx];
#pragma unroll
      for (int u = 0; u < 4; ++u) {
        const bf16x8 b = *(const bf16x8*)&Bs[(u * 16 + lm) * 64 + gx];
        acc[0][u] = __builtin_amdgcn_mfma_f32_16x16x32_bf16(a0, b, acc[0][u], 0, 0, 0);
        acc[1][u] = __builtin_amdgcn_mfma_f32_16x16x32_bf16(a1, b, acc[1][u], 0, 0, 0);
      }
    }
  }
#pragma unroll
  for (int u = 0; u < 4; ++u) {
    const int n = n0 + u * 16 + lm;
    const float bias = pb[n];
#pragma unroll
    for (int s = 0; s < 2; ++s) {
#pragma unroll
      for (int rg = 0; rg < 4; ++rg) {
        const int m = m0 + wv * 32 + s * 16 + quad * 4 + rg;
        out[(size_t)m * DIMN + n] = gelu_f(acc[s][u][rg] + bias);
      }
    }
  }
}

extern "C" void kernel_launch(void* const* d_in, const int* in_sizes, int n_in,
                              void* d_out, int out_size, void* d_ws, size_t ws_size,
                              hipStream_t stream) {
  const float* x = (const float*)d_in[0];
  const float* conv_w = (const float*)d_in[1];
  const float* conv_b = (const float*)d_in[2];
  const float* bn_gamma = (const float*)d_in[3];
  const float* bn_beta = (const float*)d_in[4];
  const float* bn_mean = (const float*)d_in[5];
  const float* bn_var = (const float*)d_in[6];
  const float* proj_w = (const float*)d_in[7];
  const float* proj_b = (const float*)d_in[8];
  const float* mask = (const float*)d_in[9];
  float* out = (float*)d_out;         // [tokens][patches], fp32
  float* patches = out + TOKN;
  u16* ws = (u16*)d_ws;
  u16* xhwc = ws;                     // later reused as A bf16
  u16* bp = ws + BP_OFF;
  u16* pw = ws + PW_OFF;

  hipMemsetAsync(d_ws, 0, XHWC_ELEMS * sizeof(u16), stream);  // zero halo
  k_transpose<<<NFRM * HW, 256, 0, stream>>>(x, xhwc);
  k_bpack<<<144, 256, 0, stream>>>(conv_w, bp);
  k_pw<<<1728, 256, 0, stream>>>(proj_w, pw);
  k_conv<<<NFRM * 32, 256, 0, stream>>>(xhwc, bp, conv_b, bn_gamma, bn_beta,
                                        bn_mean, bn_var, mask, patches);
  k_cvt<<<18432, 256, 0, stream>>>(patches, xhwc);  // xhwc dead after k_conv
  k_gemm<<<64 * 12, 256, 0, stream>>>(xhwc, pw, proj_b, out);
}